// Round 14
// baseline (1823.498 us; speedup 1.0000x reference)
//
#include <hip/hip_runtime.h>
#include <math.h>

#define LOG2E 1.4426950408889634f
#define LN2   0.6931471805599453f

typedef short    short8  __attribute__((ext_vector_type(8)));
typedef float    floatx4 __attribute__((ext_vector_type(4)));
typedef _Float16 half8   __attribute__((ext_vector_type(8)));

__constant__ int c_pi[28] = {0,0,0,0,0,0,0,1,1,1,1,1,1,2,2,2,2,2,3,3,3,3,4,4,4,5,5,6};
__constant__ int c_pj[28] = {1,2,3,4,5,6,7,2,3,4,5,6,7,3,4,5,6,7,4,5,6,7,5,6,7,6,7,7};

// ---------------- static device storage ----------------
__device__ unsigned short g_cellsL[16*256*256];   // bf16 bits, gathered local cells
__device__ unsigned short g_cellsG[8*512*256];    // bf16 bits, gathered global cells
__device__ float g_x2L[16*256];
__device__ float g_x2G[8*512];
__device__ int   g_idxL[16*256];
__device__ int   g_idxG[8*512];
// fp16 cost matrices. Local: [0,56)=Cxy, [56,112)=Cyx(T), [112,128)=Cxx. 16.8 MB
// -> L3-resident in k_iter (cached loads).
__device__ _Float16 g_CL[128*256*256];
// Global: [0,28)=Cxy, [28,56)=Cyx(T), [56,64)=Cxx. 33.6 MB
// -> HBM-streamed in k_iter (non-temporal loads) so the L3 path (~3.6 TB/s)
// and HBM path (~6.3 TB/s) serve the two sets concurrently (r12 measured
// best at 12.9 us/launch vs 13.4 all-NT).
__device__ _Float16 g_CG[64*512*512];
__device__ float g_fL[2][56*256];
__device__ float g_gL[2][56*256];
__device__ float g_pxL[2][16*256];
__device__ float g_fG[2][28*512];
__device__ float g_gG[2][28*512];
__device__ float g_pxG[2][8*512];

// ---------------- helpers ----------------
__device__ __forceinline__ unsigned short f2bf(float f) {
    unsigned u = __float_as_uint(f);
    u += 0x7fffu + ((u >> 16) & 1u);          // RNE; inputs are finite
    return (unsigned short)(u >> 16);
}

// ---------------- index lists: first-m matches in order (ballot scan) -------
__global__ void k_index(const int* __restrict__ labels, const int* __restrict__ subg) {
    int b = blockIdx.x, lane = threadIdx.x;   // 24 blocks x 64 threads
    int want_l, want_s, cap; int* out;
    if (b < 16) { want_l = b >> 3; want_s = b & 7; cap = 256; out = g_idxL + b*256; }
    else        { want_l = -1;     want_s = b - 16; cap = 512; out = g_idxG + (b-16)*512; }
    int cnt = 0;
    for (int base = 0; base < 4096; base += 64) {
        int i = base + lane;
        bool m = (subg[i] == want_s) && (want_l < 0 || labels[i] == want_l);
        unsigned long long mask = __ballot(m);
        int pos = cnt + __popcll(mask & ((1ull << lane) - 1ull));
        if (m && pos < cap) out[pos] = i;
        cnt += __popcll(mask);
    }
}

// ---------------- gather rows -> bf16 cells + fp32 sq-norms -----------------
__global__ void k_gather(const float* __restrict__ feat) {
    int wv = blockIdx.x*4 + (threadIdx.x >> 6);   // 8192 waves, one row each
    int lane = threadIdx.x & 63;
    const float* src; unsigned short* dst; float* x2out;
    if (wv < 4096) {
        int c = wv >> 8, row = wv & 255;
        src = feat + (size_t)g_idxL[c*256+row]*256;
        dst = g_cellsL + (size_t)(c*256+row)*256;
        x2out = g_x2L + c*256 + row;
    } else {
        int v = wv - 4096; int c = v >> 9, row = v & 511;
        src = feat + (size_t)g_idxG[c*512+row]*256;
        dst = g_cellsG + (size_t)(c*512+row)*256;
        x2out = g_x2G + c*512 + row;
    }
    floatx4 v4 = *(const floatx4*)(src + lane*4);
    float s = v4[0]*v4[0] + v4[1]*v4[1] + v4[2]*v4[2] + v4[3]*v4[3];
    unsigned lo = (unsigned)f2bf(v4[0]) | ((unsigned)f2bf(v4[1]) << 16);
    unsigned hi = (unsigned)f2bf(v4[2]) | ((unsigned)f2bf(v4[3]) << 16);
    unsigned* d32 = (unsigned*)dst;
    d32[lane*2] = lo; d32[lane*2+1] = hi;
    for (int o = 32; o; o >>= 1) s += __shfl_xor(s, o);
    if (lane == 0) *x2out = s;
}

// ---------------- cost matrices via bf16 MFMA (wave = 16x64 output tile) ----
// C_ij = 0.5*max(x2_i + y2_j - 2*x.y, 0), stored fp16. 4 tj-tiles share one A
// fragment (5 loads + 4 MFMAs per k-step). Stores are NORMAL (cached): r13's
// NT 2B-granularity stores caused 3.2x partial-line write amplification
// (WRITE 61->162 MB); L2 write-combining coalesces normal stores (r11: 61 MB).
__global__ void k_gemm() {
    int job = blockIdx.x*4 + (threadIdx.x >> 6);   // 6144 blocks -> 24576 jobs
    int lane = threadIdx.x & 63;
    const unsigned short *A, *B; _Float16* Cout; const float *x2a, *x2b;
    int m, ti, tjq;
    if (job < 8192) {                       // local: 128 matrices x 64 jobs (16x4)
        int mm = job >> 6, t = job & 63; ti = t >> 2; tjq = t & 3; m = 256;
        int ca, cb;
        if (mm < 56)       { int lbl = mm/28,  q = mm%28;  ca = lbl*8 + c_pi[q]; cb = lbl*8 + c_pj[q]; }
        else if (mm < 112) { int p = mm-56; int lbl = p/28, q = p%28;
                             ca = lbl*8 + c_pj[q]; cb = lbl*8 + c_pi[q]; }
        else               { int c = mm-112; ca = cb = c; }
        A = g_cellsL + (size_t)ca*65536; B = g_cellsL + (size_t)cb*65536;
        x2a = g_x2L + ca*256; x2b = g_x2L + cb*256;
        Cout = g_CL + (size_t)mm*65536;
    } else {                                // global: 64 matrices x 256 jobs (32x8)
        int jj = job - 8192; int mm = jj >> 8, t = jj & 255; ti = t >> 3; tjq = t & 7; m = 512;
        int ca, cb;
        if (mm < 28)      { ca = c_pi[mm];    cb = c_pj[mm]; }
        else if (mm < 56) { ca = c_pj[mm-28]; cb = c_pi[mm-28]; }
        else              { ca = cb = mm-56; }
        A = g_cellsG + (size_t)ca*131072; B = g_cellsG + (size_t)cb*131072;
        x2a = g_x2G + ca*512; x2b = g_x2G + cb*512;
        Cout = g_CG + (size_t)mm*262144;
    }
    int r = lane & 15, quad = lane >> 4;
    const unsigned short* Ap = A + (size_t)(ti*16 + r)*256 + quad*8;
    const unsigned short* Bp = B + (size_t)(tjq*64 + r)*256 + quad*8;
    floatx4 acc0 = {0.f,0.f,0.f,0.f}, acc1 = {0.f,0.f,0.f,0.f};
    floatx4 acc2 = {0.f,0.f,0.f,0.f}, acc3 = {0.f,0.f,0.f,0.f};
    #pragma unroll
    for (int k = 0; k < 256; k += 32) {
        short8 av  = *(const short8*)(Ap + k);
        short8 bv0 = *(const short8*)(Bp + k);
        short8 bv1 = *(const short8*)(Bp + (size_t)16*256 + k);
        short8 bv2 = *(const short8*)(Bp + (size_t)32*256 + k);
        short8 bv3 = *(const short8*)(Bp + (size_t)48*256 + k);
        acc0 = __builtin_amdgcn_mfma_f32_16x16x32_bf16(av, bv0, acc0, 0, 0, 0);
        acc1 = __builtin_amdgcn_mfma_f32_16x16x32_bf16(av, bv1, acc1, 0, 0, 0);
        acc2 = __builtin_amdgcn_mfma_f32_16x16x32_bf16(av, bv2, acc2, 0, 0, 0);
        acc3 = __builtin_amdgcn_mfma_f32_16x16x32_bf16(av, bv3, acc3, 0, 0, 0);
    }
    float accs[4][4] = {
        {acc0[0],acc0[1],acc0[2],acc0[3]}, {acc1[0],acc1[1],acc1[2],acc1[3]},
        {acc2[0],acc2[1],acc2[2],acc2[3]}, {acc3[0],acc3[1],acc3[2],acc3[3]} };
    #pragma unroll
    for (int n = 0; n < 4; n++) {
        int jc = tjq*64 + n*16 + r;         // D: col = lane&15, row = quad*4 + reg
        float y2 = x2b[jc];
        #pragma unroll
        for (int rr = 0; rr < 4; rr++) {
            int ir = ti*16 + quad*4 + rr;
            float v = x2a[ir] + y2 - 2.f*accs[n][rr];
            Cout[(size_t)ir*m + jc] = (_Float16)(0.5f*fmaxf(v, 0.f));
        }
    }
}

// ---------------- zero the parity-0 potential buffers -----------------------
__global__ void k_init() {
    int t = blockIdx.x*256 + threadIdx.x;   // 65536 threads
    if      (t < 14336) g_fL[0][t] = 0.f;
    else if (t < 28672) g_gL[0][t-14336] = 0.f;
    else if (t < 32768) g_pxL[0][t-28672] = 0.f;
    else if (t < 47104) g_fG[0][t-32768] = 0.f;
    else if (t < 61440) g_gG[0][t-47104] = 0.f;
    else                g_pxG[0][t-61440] = 0.f;
}

// ---------------- row softmin pass, fully register-resident -----------------
// ft_i = -eps*LSE_j(h_j - C_ij/eps); every pass is a row pass (T materialized).
// M=256: half-wave per row (lanes 0-31 / 32-63), 2*STEPS rows/wave.
// M=512: full wave per row, STEPS rows/wave.
// STEPS=6 main stripes (6 KB/wave), STEPS=2 tail stripes (2 KB/wave).
// 4-deep C prefetch ring + upfront f_old preload. NT=1: non-temporal C loads
// (global matrices stream from HBM); NT=0: cached (locals ride L3).
template<int M, int STEPS, int NT>
__device__ __forceinline__ void sm_pass(const _Float16* __restrict__ C,
    const float* __restrict__ hsrc, const float* __restrict__ fold,
    float* __restrict__ fout, int r0, float eps, float inv_eps, float loga,
    int hard, int fin)
{
    const int W = (M == 256) ? 16 : 32;     // shfl butterfly start
    int tid = threadIdx.x, lane = tid & 63, w = tid >> 6;
    int co = (M == 256) ? (lane & 31) : lane;
    float h[8];
    floatx4 h0 = *(const floatx4*)(hsrc + co*8);
    floatx4 h1 = *(const floatx4*)(hsrc + co*8 + 4);
    #pragma unroll
    for (int k = 0; k < 4; k++) { h[k] = loga + h0[k]*inv_eps; h[4+k] = loga + h1[k]*inv_eps; }
    int rbase = (M == 256) ? (r0 + w*2*STEPS) : (r0 + w*STEPS);
    int rowst = (M == 256) ? 2 : 1;
    int radd  = (M == 256) ? (lane >> 5) : 0;
    bool wr   = (M == 256) ? ((lane & 31) == 0) : (lane == 0);
    int rr0 = rbase + radd;

    const _Float16* cp = C + (size_t)rr0*M + co*8;
    float fArr[STEPS];
    #pragma unroll
    for (int s = 0; s < STEPS; s++) fArr[s] = fold[rr0 + rowst*s];
    half8 cb[4];
    #pragma unroll
    for (int s = 0; s < 3; s++)
        if (s < STEPS) {
            const half8* p = (const half8*)(cp + (size_t)rowst*M*s);
            cb[s] = NT ? __builtin_nontemporal_load(p) : *p;
        }
    #pragma unroll
    for (int s = 0; s < STEPS; s++) {
        if (s + 3 < STEPS) {
            const half8* p = (const half8*)(cp + (size_t)rowst*M*(s+3));
            cb[(s+3)&3] = NT ? __builtin_nontemporal_load(p) : *p;
        }
        half8 cv = cb[s&3];
        float tv[8]; float mx = -3.4e38f;
        #pragma unroll
        for (int k = 0; k < 8; k++) {
            float t = h[k] - (float)cv[k]*inv_eps;
            tv[k] = t; mx = fmaxf(mx, t);
        }
        #pragma unroll
        for (int o = W; o; o >>= 1) mx = fmaxf(mx, __shfl_xor(mx, o));
        float ft;
        if (!hard) {
            float sum = 0.f;
            #pragma unroll
            for (int k = 0; k < 8; k++) sum += exp2f((tv[k] - mx)*LOG2E);
            #pragma unroll
            for (int o = W; o; o >>= 1) sum += __shfl_xor(sum, o);
            ft = -eps*(mx + LN2*__log2f(sum));
        } else {
            ft = -eps*mx;                   // |err| <= eps*ln(M), negligible for eps<1e-5
        }
        if (wr) {
            int row = rr0 + rowst*s;
            fout[row] = fin ? ft : 0.5f*(fArr[s] + ft);
        }
    }
}

// ---------------- one eps-scaling iteration -------------------------------
// 2176 blocks, 8704 waves (7936 main @6KB + 768 tail @2KB), tails first so
// the 128 deferred blocks backfill behind them (cap = 8192 resident waves).
//  b <   64 : global tail   : matrix m=b,        rows [504,512), STEPS=2
//  b <  192 : local  tail   : matrix m=b-64,     rows [240,256), STEPS=2
//  b < 1536 : global main   : m=(b-192)/21, stripe r0=((b-192)%21)*24, STEPS=6
//  else     : local  main   : m=(b-1536)/5, stripe r0=((b-1536)%5)*48, STEPS=6
__global__ void __launch_bounds__(256) k_iter(float eps, float inv_eps, int par,
                                              int hard, int fin) {
    const float LGA = -5.545177444479562f;  // -ln 256
    const float LGG = -6.238324625039508f;  // -ln 512
    int b = blockIdx.x;
    int po = par, pn = par ^ 1;
    bool isG, tail; int m, r0;
    if (b < 64)        { isG = true;  tail = true;  m = b;        r0 = 504; }
    else if (b < 192)  { isG = false; tail = true;  m = b - 64;   r0 = 240; }
    else if (b < 1536) { int t = b - 192;  isG = true;  tail = false; m = t/21; r0 = (t%21)*24; }
    else               { int t = b - 1536; isG = false; tail = false; m = t/5;  r0 = (t%5)*48; }
    if (isG) {
        const _Float16* C = g_CG + (size_t)m*262144;
        const float *h, *fo; float* fn;
        if (m < 28)      { h = g_gG[po]+m*512;  fo = g_fG[po]+m*512;  fn = g_fG[pn]+m*512; }
        else if (m < 56) { int p = m-28;  h = g_fG[po]+p*512;  fo = g_gG[po]+p*512;  fn = g_gG[pn]+p*512; }
        else             { int c = m-56;  h = g_pxG[po]+c*512; fo = h;               fn = g_pxG[pn]+c*512; }
        if (tail) sm_pass<512,2,1>(C, h, fo, fn, r0, eps, inv_eps, LGG, hard, fin);
        else      sm_pass<512,6,1>(C, h, fo, fn, r0, eps, inv_eps, LGG, hard, fin);
    } else {
        const _Float16* C = g_CL + (size_t)m*65536;
        const float *h, *fo; float* fn;
        if (m < 56)       { h = g_gL[po]+m*256;  fo = g_fL[po]+m*256;  fn = g_fL[pn]+m*256; }
        else if (m < 112) { int p = m-56;  h = g_fL[po]+p*256;  fo = g_gL[po]+p*256;  fn = g_gL[pn]+p*256; }
        else              { int c = m-112; h = g_pxL[po]+c*256; fo = h;               fn = g_pxL[pn]+c*256; }
        if (tail) sm_pass<256,2,0>(C, h, fo, fn, r0, eps, inv_eps, LGA, hard, fin);
        else      sm_pass<256,6,0>(C, h, fo, fn, r0, eps, inv_eps, LGA, hard, fin);
    }
}

// ---------------- final reduction to the scalar loss ------------------------
__global__ void k_combine(float* __restrict__ out) {
    __shared__ float red[4][4];
    int tid = threadIdx.x;                  // 256 threads
    float sfg_l = 0.f, spx_l = 0.f, sfg_g = 0.f, spx_g = 0.f;
    for (int i = tid; i < 14336; i += 256) sfg_l += g_fL[1][i] + g_gL[1][i];
    for (int i = tid; i < 4096;  i += 256) spx_l += g_pxL[1][i];
    for (int i = tid; i < 14336; i += 256) sfg_g += g_fG[1][i] + g_gG[1][i];
    for (int i = tid; i < 4096;  i += 256) spx_g += g_pxG[1][i];
    for (int o = 32; o; o >>= 1) {
        sfg_l += __shfl_xor(sfg_l, o); spx_l += __shfl_xor(spx_l, o);
        sfg_g += __shfl_xor(sfg_g, o); spx_g += __shfl_xor(spx_g, o);
    }
    int w = tid >> 6;
    if ((tid & 63) == 0) { red[0][w] = sfg_l; red[1][w] = spx_l; red[2][w] = sfg_g; red[3][w] = spx_g; }
    __syncthreads();
    if (tid == 0) {
        float SL = red[0][0]+red[0][1]+red[0][2]+red[0][3];
        float PL = red[1][0]+red[1][1]+red[1][2]+red[1][3];
        float SG = red[2][0]+red[2][1]+red[2][2]+red[2][3];
        float PG = red[3][0]+red[3][1]+red[3][2]+red[3][3];
        float local_l  = SL/14336.f - PL/2048.f;
        float global_l = SG/14336.f - PG/2048.f;
        out[0] = 1.0f*local_l + 0.5f*global_l;
    }
}

// ---------------- host launcher ---------------------------------------------
extern "C" void kernel_launch(void* const* d_in, const int* in_sizes, int n_in,
                              void* d_out, int out_size, void* d_ws, size_t ws_size,
                              hipStream_t stream) {
    (void)in_sizes; (void)n_in; (void)out_size; (void)d_ws; (void)ws_size;
    const float* feat  = (const float*)d_in[0];
    const int* labels  = (const int*)d_in[1];
    const int* subg    = (const int*)d_in[2];

    k_index <<<24,    64, 0, stream>>>(labels, subg);
    k_gather<<<2048, 256, 0, stream>>>(feat);
    k_gemm  <<<6144, 256, 0, stream>>>();   // 24576 jobs (16x64 tiles), 4/block
    k_init  <<<256,  256, 0, stream>>>();

    // eps schedule identical to reference (double, like numpy)
    double eps0 = 4.0*256.0, ratio = 0.9*0.9, target = 1e-4*1e-4;
    int n = (int)ceil(log(target/eps0)/log(ratio));    // 121 -> 122 iterations
    float ef = 1e-8f;
    for (int k = 0; k <= n; k++) {
        double e = eps0 * pow(ratio, (double)k);
        if (e < target) e = target;
        ef = (float)e;
        int hard = (ef < 1e-5f) ? 1 : 0;
        k_iter<<<2176, 256, 0, stream>>>(ef, (float)(1.0/(double)ef), k & 1, hard, 0);
    }
    // final extrapolation at eps_f (reads parity 0 carry, writes raw to parity 1)
    k_iter<<<2176, 256, 0, stream>>>(ef, (float)(1.0/(double)ef), 0, 1, 1);
    k_combine<<<1, 256, 0, stream>>>((float*)d_out);
}

// Round 15
// 1810.399 us; speedup vs baseline: 1.0072x; 1.0072x over previous
//
#include <hip/hip_runtime.h>
#include <math.h>

#define LOG2E 1.4426950408889634f
#define LN2   0.6931471805599453f

typedef short    short8  __attribute__((ext_vector_type(8)));
typedef float    floatx4 __attribute__((ext_vector_type(4)));
typedef _Float16 half8   __attribute__((ext_vector_type(8)));

__constant__ int c_pi[28] = {0,0,0,0,0,0,0,1,1,1,1,1,1,2,2,2,2,2,3,3,3,3,4,4,4,5,5,6};
__constant__ int c_pj[28] = {1,2,3,4,5,6,7,2,3,4,5,6,7,3,4,5,6,7,4,5,6,7,5,6,7,6,7,7};

// ---------------- static device storage ----------------
__device__ unsigned short g_cellsL[16*256*256];   // bf16 bits, gathered local cells
__device__ unsigned short g_cellsG[8*512*256];    // bf16 bits, gathered global cells
__device__ float g_x2L[16*256];
__device__ float g_x2G[8*512];
__device__ int   g_idxL[16*256];
__device__ int   g_idxG[8*512];
// fp16 cost matrices. Local: [0,56)=Cxy, [56,112)=Cyx(T), [112,128)=Cxx. 16.8 MB
// -> L3-resident in k_iter (cached loads).
__device__ _Float16 g_CL[128*256*256];
// Global: [0,28)=Cxy, [28,56)=Cyx(T), [56,64)=Cxx. 33.6 MB
// -> HBM-streamed in k_iter (non-temporal loads): L3 path (~3.6 TB/s) and HBM
// path serve the two sets concurrently.
__device__ _Float16 g_CG[64*512*512];
__device__ float g_fL[2][56*256];
__device__ float g_gL[2][56*256];
__device__ float g_pxL[2][16*256];
__device__ float g_fG[2][28*512];
__device__ float g_gG[2][28*512];
__device__ float g_pxG[2][8*512];

// ---------------- helpers ----------------
__device__ __forceinline__ unsigned short f2bf(float f) {
    unsigned u = __float_as_uint(f);
    u += 0x7fffu + ((u >> 16) & 1u);          // RNE; inputs are finite
    return (unsigned short)(u >> 16);
}

// ---------------- index lists: first-m matches in order (ballot scan) -------
__global__ void k_index(const int* __restrict__ labels, const int* __restrict__ subg) {
    int b = blockIdx.x, lane = threadIdx.x;   // 24 blocks x 64 threads
    int want_l, want_s, cap; int* out;
    if (b < 16) { want_l = b >> 3; want_s = b & 7; cap = 256; out = g_idxL + b*256; }
    else        { want_l = -1;     want_s = b - 16; cap = 512; out = g_idxG + (b-16)*512; }
    int cnt = 0;
    for (int base = 0; base < 4096; base += 64) {
        int i = base + lane;
        bool m = (subg[i] == want_s) && (want_l < 0 || labels[i] == want_l);
        unsigned long long mask = __ballot(m);
        int pos = cnt + __popcll(mask & ((1ull << lane) - 1ull));
        if (m && pos < cap) out[pos] = i;
        cnt += __popcll(mask);
    }
}

// ---------------- gather rows -> bf16 cells + fp32 sq-norms -----------------
__global__ void k_gather(const float* __restrict__ feat) {
    int wv = blockIdx.x*4 + (threadIdx.x >> 6);   // 8192 waves, one row each
    int lane = threadIdx.x & 63;
    const float* src; unsigned short* dst; float* x2out;
    if (wv < 4096) {
        int c = wv >> 8, row = wv & 255;
        src = feat + (size_t)g_idxL[c*256+row]*256;
        dst = g_cellsL + (size_t)(c*256+row)*256;
        x2out = g_x2L + c*256 + row;
    } else {
        int v = wv - 4096; int c = v >> 9, row = v & 511;
        src = feat + (size_t)g_idxG[c*512+row]*256;
        dst = g_cellsG + (size_t)(c*512+row)*256;
        x2out = g_x2G + c*512 + row;
    }
    floatx4 v4 = *(const floatx4*)(src + lane*4);
    float s = v4[0]*v4[0] + v4[1]*v4[1] + v4[2]*v4[2] + v4[3]*v4[3];
    unsigned lo = (unsigned)f2bf(v4[0]) | ((unsigned)f2bf(v4[1]) << 16);
    unsigned hi = (unsigned)f2bf(v4[2]) | ((unsigned)f2bf(v4[3]) << 16);
    unsigned* d32 = (unsigned*)dst;
    d32[lane*2] = lo; d32[lane*2+1] = hi;
    for (int o = 32; o; o >>= 1) s += __shfl_xor(s, o);
    if (lane == 0) *x2out = s;
}

// ---------------- cost matrices via bf16 MFMA (wave = 16x64 output tile) ----
// C_ij = 0.5*max(x2_i + y2_j - 2*x.y, 0), stored fp16 (normal cached stores;
// NT 2B stores caused 3.2x partial-line write amplification in r13).
// Manual 2-stage software pipeline: r13/r14's VGPR_Count=32 proves hipcc
// serialized the loads; explicit next-set registers force ~5 loads in flight
// against each k-step's 4 MFMAs (kernel is pure load-latency-bound:
// MfmaUtil 4%, VALUBusy 5.8%, Occ 77%).
__global__ void k_gemm() {
    int job = blockIdx.x*4 + (threadIdx.x >> 6);   // 6144 blocks -> 24576 jobs
    int lane = threadIdx.x & 63;
    const unsigned short *A, *B; _Float16* Cout; const float *x2a, *x2b;
    int m, ti, tjq;
    if (job < 8192) {                       // local: 128 matrices x 64 jobs (16x4)
        int mm = job >> 6, t = job & 63; ti = t >> 2; tjq = t & 3; m = 256;
        int ca, cb;
        if (mm < 56)       { int lbl = mm/28,  q = mm%28;  ca = lbl*8 + c_pi[q]; cb = lbl*8 + c_pj[q]; }
        else if (mm < 112) { int p = mm-56; int lbl = p/28, q = p%28;
                             ca = lbl*8 + c_pj[q]; cb = lbl*8 + c_pi[q]; }
        else               { int c = mm-112; ca = cb = c; }
        A = g_cellsL + (size_t)ca*65536; B = g_cellsL + (size_t)cb*65536;
        x2a = g_x2L + ca*256; x2b = g_x2L + cb*256;
        Cout = g_CL + (size_t)mm*65536;
    } else {                                // global: 64 matrices x 256 jobs (32x8)
        int jj = job - 8192; int mm = jj >> 8, t = jj & 255; ti = t >> 3; tjq = t & 7; m = 512;
        int ca, cb;
        if (mm < 28)      { ca = c_pi[mm];    cb = c_pj[mm]; }
        else if (mm < 56) { ca = c_pj[mm-28]; cb = c_pi[mm-28]; }
        else              { ca = cb = mm-56; }
        A = g_cellsG + (size_t)ca*131072; B = g_cellsG + (size_t)cb*131072;
        x2a = g_x2G + ca*512; x2b = g_x2G + cb*512;
        Cout = g_CG + (size_t)mm*262144;
    }
    int r = lane & 15, quad = lane >> 4;
    const unsigned short* Ap = A + (size_t)(ti*16 + r)*256 + quad*8;
    const unsigned short* Bp = B + (size_t)(tjq*64 + r)*256 + quad*8;
    floatx4 acc0 = {0.f,0.f,0.f,0.f}, acc1 = {0.f,0.f,0.f,0.f};
    floatx4 acc2 = {0.f,0.f,0.f,0.f}, acc3 = {0.f,0.f,0.f,0.f};
    short8 av  = *(const short8*)(Ap);
    short8 bv0 = *(const short8*)(Bp);
    short8 bv1 = *(const short8*)(Bp + (size_t)16*256);
    short8 bv2 = *(const short8*)(Bp + (size_t)32*256);
    short8 bv3 = *(const short8*)(Bp + (size_t)48*256);
    #pragma unroll
    for (int k = 0; k < 256; k += 32) {
        short8 nav = av, nbv0 = bv0, nbv1 = bv1, nbv2 = bv2, nbv3 = bv3;
        if (k < 224) {                      // issue next set before MFMAs
            nav  = *(const short8*)(Ap + k + 32);
            nbv0 = *(const short8*)(Bp + k + 32);
            nbv1 = *(const short8*)(Bp + (size_t)16*256 + k + 32);
            nbv2 = *(const short8*)(Bp + (size_t)32*256 + k + 32);
            nbv3 = *(const short8*)(Bp + (size_t)48*256 + k + 32);
        }
        acc0 = __builtin_amdgcn_mfma_f32_16x16x32_bf16(av, bv0, acc0, 0, 0, 0);
        acc1 = __builtin_amdgcn_mfma_f32_16x16x32_bf16(av, bv1, acc1, 0, 0, 0);
        acc2 = __builtin_amdgcn_mfma_f32_16x16x32_bf16(av, bv2, acc2, 0, 0, 0);
        acc3 = __builtin_amdgcn_mfma_f32_16x16x32_bf16(av, bv3, acc3, 0, 0, 0);
        av = nav; bv0 = nbv0; bv1 = nbv1; bv2 = nbv2; bv3 = nbv3;
    }
    float accs[4][4] = {
        {acc0[0],acc0[1],acc0[2],acc0[3]}, {acc1[0],acc1[1],acc1[2],acc1[3]},
        {acc2[0],acc2[1],acc2[2],acc2[3]}, {acc3[0],acc3[1],acc3[2],acc3[3]} };
    #pragma unroll
    for (int n = 0; n < 4; n++) {
        int jc = tjq*64 + n*16 + r;         // D: col = lane&15, row = quad*4 + reg
        float y2 = x2b[jc];
        #pragma unroll
        for (int rr = 0; rr < 4; rr++) {
            int ir = ti*16 + quad*4 + rr;
            float v = x2a[ir] + y2 - 2.f*accs[n][rr];
            Cout[(size_t)ir*m + jc] = (_Float16)(0.5f*fmaxf(v, 0.f));
        }
    }
}

// ---------------- zero the parity-0 potential buffers -----------------------
__global__ void k_init() {
    int t = blockIdx.x*256 + threadIdx.x;   // 65536 threads
    if      (t < 14336) g_fL[0][t] = 0.f;
    else if (t < 28672) g_gL[0][t-14336] = 0.f;
    else if (t < 32768) g_pxL[0][t-28672] = 0.f;
    else if (t < 47104) g_fG[0][t-32768] = 0.f;
    else if (t < 61440) g_gG[0][t-47104] = 0.f;
    else                g_pxG[0][t-61440] = 0.f;
}

// ---------------- row softmin pass, fully register-resident -----------------
// ft_i = -eps*LSE_j(h_j - C_ij/eps); every pass is a row pass (T materialized).
// M=256: half-wave per row, 2*STEPS rows/wave. M=512: full wave, STEPS rows.
// STEPS=6 main stripes (6 KB/wave), STEPS=2 tails. ALL rows preloaded upfront
// (6 outstanding 1KB loads/wave, up from ring-4's 3 — VGPR ~56, under the
// 64-VGPR occupancy cliff). NT=1: non-temporal (globals via HBM path).
template<int M, int STEPS, int NT>
__device__ __forceinline__ void sm_pass(const _Float16* __restrict__ C,
    const float* __restrict__ hsrc, const float* __restrict__ fold,
    float* __restrict__ fout, int r0, float eps, float inv_eps, float loga,
    int hard, int fin)
{
    const int W = (M == 256) ? 16 : 32;     // shfl butterfly start
    int tid = threadIdx.x, lane = tid & 63, w = tid >> 6;
    int co = (M == 256) ? (lane & 31) : lane;
    float h[8];
    floatx4 h0 = *(const floatx4*)(hsrc + co*8);
    floatx4 h1 = *(const floatx4*)(hsrc + co*8 + 4);
    #pragma unroll
    for (int k = 0; k < 4; k++) { h[k] = loga + h0[k]*inv_eps; h[4+k] = loga + h1[k]*inv_eps; }
    int rbase = (M == 256) ? (r0 + w*2*STEPS) : (r0 + w*STEPS);
    int rowst = (M == 256) ? 2 : 1;
    int radd  = (M == 256) ? (lane >> 5) : 0;
    bool wr   = (M == 256) ? ((lane & 31) == 0) : (lane == 0);
    int rr0 = rbase + radd;

    const _Float16* cp = C + (size_t)rr0*M + co*8;
    half8 cb[STEPS];
    #pragma unroll
    for (int s = 0; s < STEPS; s++) {
        const half8* p = (const half8*)(cp + (size_t)rowst*M*s);
        cb[s] = NT ? __builtin_nontemporal_load(p) : *p;
    }
    float fArr[STEPS];
    #pragma unroll
    for (int s = 0; s < STEPS; s++) fArr[s] = fold[rr0 + rowst*s];
    #pragma unroll
    for (int s = 0; s < STEPS; s++) {
        half8 cv = cb[s];
        float tv[8]; float mx = -3.4e38f;
        #pragma unroll
        for (int k = 0; k < 8; k++) {
            float t = h[k] - (float)cv[k]*inv_eps;
            tv[k] = t; mx = fmaxf(mx, t);
        }
        #pragma unroll
        for (int o = W; o; o >>= 1) mx = fmaxf(mx, __shfl_xor(mx, o));
        float ft;
        if (!hard) {
            float sum = 0.f;
            #pragma unroll
            for (int k = 0; k < 8; k++) sum += exp2f((tv[k] - mx)*LOG2E);
            #pragma unroll
            for (int o = W; o; o >>= 1) sum += __shfl_xor(sum, o);
            ft = -eps*(mx + LN2*__log2f(sum));
        } else {
            ft = -eps*mx;                   // |err| <= eps*ln(M), negligible for eps<1e-5
        }
        if (wr) {
            int row = rr0 + rowst*s;
            fout[row] = fin ? ft : 0.5f*(fArr[s] + ft);
        }
    }
}

// ---------------- one eps-scaling iteration -------------------------------
// 2176 blocks, 8704 waves (7936 main @6KB + 768 tail @2KB), tails first so
// the 128 deferred blocks backfill behind them (cap = 8192 resident waves).
//  b <   64 : global tail   : matrix m=b,        rows [504,512), STEPS=2
//  b <  192 : local  tail   : matrix m=b-64,     rows [240,256), STEPS=2
//  b < 1536 : global main   : m=(b-192)/21, stripe r0=((b-192)%21)*24, STEPS=6
//  else     : local  main   : m=(b-1536)/5, stripe r0=((b-1536)%5)*48, STEPS=6
__global__ void __launch_bounds__(256) k_iter(float eps, float inv_eps, int par,
                                              int hard, int fin) {
    const float LGA = -5.545177444479562f;  // -ln 256
    const float LGG = -6.238324625039508f;  // -ln 512
    int b = blockIdx.x;
    int po = par, pn = par ^ 1;
    bool isG, tail; int m, r0;
    if (b < 64)        { isG = true;  tail = true;  m = b;        r0 = 504; }
    else if (b < 192)  { isG = false; tail = true;  m = b - 64;   r0 = 240; }
    else if (b < 1536) { int t = b - 192;  isG = true;  tail = false; m = t/21; r0 = (t%21)*24; }
    else               { int t = b - 1536; isG = false; tail = false; m = t/5;  r0 = (t%5)*48; }
    if (isG) {
        const _Float16* C = g_CG + (size_t)m*262144;
        const float *h, *fo; float* fn;
        if (m < 28)      { h = g_gG[po]+m*512;  fo = g_fG[po]+m*512;  fn = g_fG[pn]+m*512; }
        else if (m < 56) { int p = m-28;  h = g_fG[po]+p*512;  fo = g_gG[po]+p*512;  fn = g_gG[pn]+p*512; }
        else             { int c = m-56;  h = g_pxG[po]+c*512; fo = h;               fn = g_pxG[pn]+c*512; }
        if (tail) sm_pass<512,2,1>(C, h, fo, fn, r0, eps, inv_eps, LGG, hard, fin);
        else      sm_pass<512,6,1>(C, h, fo, fn, r0, eps, inv_eps, LGG, hard, fin);
    } else {
        const _Float16* C = g_CL + (size_t)m*65536;
        const float *h, *fo; float* fn;
        if (m < 56)       { h = g_gL[po]+m*256;  fo = g_fL[po]+m*256;  fn = g_fL[pn]+m*256; }
        else if (m < 112) { int p = m-56;  h = g_fL[po]+p*256;  fo = g_gL[po]+p*256;  fn = g_gL[pn]+p*256; }
        else              { int c = m-112; h = g_pxL[po]+c*256; fo = h;               fn = g_pxL[pn]+c*256; }
        if (tail) sm_pass<256,2,0>(C, h, fo, fn, r0, eps, inv_eps, LGA, hard, fin);
        else      sm_pass<256,6,0>(C, h, fo, fn, r0, eps, inv_eps, LGA, hard, fin);
    }
}

// ---------------- final reduction to the scalar loss ------------------------
__global__ void k_combine(float* __restrict__ out) {
    __shared__ float red[4][4];
    int tid = threadIdx.x;                  // 256 threads
    float sfg_l = 0.f, spx_l = 0.f, sfg_g = 0.f, spx_g = 0.f;
    for (int i = tid; i < 14336; i += 256) sfg_l += g_fL[1][i] + g_gL[1][i];
    for (int i = tid; i < 4096;  i += 256) spx_l += g_pxL[1][i];
    for (int i = tid; i < 14336; i += 256) sfg_g += g_fG[1][i] + g_gG[1][i];
    for (int i = tid; i < 4096;  i += 256) spx_g += g_pxG[1][i];
    for (int o = 32; o; o >>= 1) {
        sfg_l += __shfl_xor(sfg_l, o); spx_l += __shfl_xor(spx_l, o);
        sfg_g += __shfl_xor(sfg_g, o); spx_g += __shfl_xor(spx_g, o);
    }
    int w = tid >> 6;
    if ((tid & 63) == 0) { red[0][w] = sfg_l; red[1][w] = spx_l; red[2][w] = sfg_g; red[3][w] = spx_g; }
    __syncthreads();
    if (tid == 0) {
        float SL = red[0][0]+red[0][1]+red[0][2]+red[0][3];
        float PL = red[1][0]+red[1][1]+red[1][2]+red[1][3];
        float SG = red[2][0]+red[2][1]+red[2][2]+red[2][3];
        float PG = red[3][0]+red[3][1]+red[3][2]+red[3][3];
        float local_l  = SL/14336.f - PL/2048.f;
        float global_l = SG/14336.f - PG/2048.f;
        out[0] = 1.0f*local_l + 0.5f*global_l;
    }
}

// ---------------- host launcher ---------------------------------------------
extern "C" void kernel_launch(void* const* d_in, const int* in_sizes, int n_in,
                              void* d_out, int out_size, void* d_ws, size_t ws_size,
                              hipStream_t stream) {
    (void)in_sizes; (void)n_in; (void)out_size; (void)d_ws; (void)ws_size;
    const float* feat  = (const float*)d_in[0];
    const int* labels  = (const int*)d_in[1];
    const int* subg    = (const int*)d_in[2];

    k_index <<<24,    64, 0, stream>>>(labels, subg);
    k_gather<<<2048, 256, 0, stream>>>(feat);
    k_gemm  <<<6144, 256, 0, stream>>>();   // 24576 jobs (16x64 tiles), 4/block
    k_init  <<<256,  256, 0, stream>>>();

    // eps schedule identical to reference (double, like numpy)
    double eps0 = 4.0*256.0, ratio = 0.9*0.9, target = 1e-4*1e-4;
    int n = (int)ceil(log(target/eps0)/log(ratio));    // 121 -> 122 iterations
    float ef = 1e-8f;
    for (int k = 0; k <= n; k++) {
        double e = eps0 * pow(ratio, (double)k);
        if (e < target) e = target;
        ef = (float)e;
        int hard = (ef < 1e-5f) ? 1 : 0;
        k_iter<<<2176, 256, 0, stream>>>(ef, (float)(1.0/(double)ef), k & 1, hard, 0);
    }
    // final extrapolation at eps_f (reads parity 0 carry, writes raw to parity 1)
    k_iter<<<2176, 256, 0, stream>>>(ef, (float)(1.0/(double)ef), 0, 1, 1);
    k_combine<<<1, 256, 0, stream>>>((float*)d_out);
}